// Round 1
// baseline (121.329 us; speedup 1.0000x reference)
//
#include <hip/hip_runtime.h>
#include <hip/hip_bf16.h>

// Problem constants (match reference)
constexpr int B  = 8;
constexpr int NQ = 256;
constexpr int NK = 512;
constexpr int D  = 256;   // DQ == DK == 256
constexpr int DV = 256;
constexpr int H  = 64;
constexpr float NEG = -1e6f;
constexpr float LOG2E = 1.4426950408889634f;

// ---------------------------------------------------------------------------
// Kernel 1: project queries and keys.  out[r,h] = sum_d in[r,d] * W[d,h]
// 4 rows per block, 256 threads: thread (r = t>>6, h = t&63).
// Rows staged in LDS (broadcast reads); W columns read coalesced (L1-resident).
// ---------------------------------------------------------------------------
__global__ __launch_bounds__(256) void proj_kernel(
    const float* __restrict__ queries, const float* __restrict__ keys,
    const float* __restrict__ Wq, const float* __restrict__ Wk,
    float* __restrict__ qp, float* __restrict__ kp)
{
    const int r0 = blockIdx.x * 4;          // 4 rows per block
    const bool isQ = (r0 < B * NQ);         // q-rows first (2048), then k-rows (4096)
    const float* src = isQ ? queries + (size_t)r0 * D
                           : keys + (size_t)(r0 - B * NQ) * D;
    const float* W   = isQ ? Wq : Wk;
    float* out       = isQ ? qp + (size_t)r0 * H
                           : kp + (size_t)(r0 - B * NQ) * H;

    __shared__ __align__(16) float rows[4][D];
    // 4 rows * 256 floats = 256 float4s, one per thread
    ((float4*)&rows[0][0])[threadIdx.x] = ((const float4*)src)[threadIdx.x];
    __syncthreads();

    const int r = threadIdx.x >> 6;
    const int h = threadIdx.x & 63;
    float s = 0.f;
#pragma unroll 4
    for (int d4 = 0; d4 < D / 4; ++d4) {
        float4 rv = *(const float4*)&rows[r][d4 * 4];
        s = fmaf(rv.x, W[(d4 * 4 + 0) * H + h], s);
        s = fmaf(rv.y, W[(d4 * 4 + 1) * H + h], s);
        s = fmaf(rv.z, W[(d4 * 4 + 2) * H + h], s);
        s = fmaf(rv.w, W[(d4 * 4 + 3) * H + h], s);
    }
    out[r * H + h] = s;
}

// ---------------------------------------------------------------------------
// Kernel 2: scores + masked softmax + attn@V.
// Grid: B * (NQ/4) = 512 blocks, 256 threads = 4 waves.  Wave w <-> query q0+w.
// Keys staged in LDS in tiles of 128, layout [k][h] with row stride 68 floats
// (16B aligned, bank pattern uniformly distributed for b128 reads).
// tanh(x) = 1 - 2*rcp(exp2(2x*log2e) + 1); score = sum_wv + sum_h (-2 wv_h) r_h.
// ---------------------------------------------------------------------------
constexpr int KT   = 128;   // keys per LDS tile
constexpr int KPAD = 68;    // row stride (floats): 68*4 = 272 B, 16B-aligned

__global__ __launch_bounds__(256) void attn_kernel(
    const float* __restrict__ qp, const float* __restrict__ kp,
    const float* __restrict__ values, const int* __restrict__ valid_lens,
    const float* __restrict__ wv, float* __restrict__ out)
{
    const int b  = blockIdx.x >> 6;          // batch
    const int q0 = (blockIdx.x & 63) * 4;    // first query of this block
    const int t  = threadIdx.x;
    const int w  = t >> 6;                   // wave id == local query index
    const int l  = t & 63;                   // lane

    __shared__ __align__(16) float kT[KT * KPAD];
    __shared__ __align__(16) float qv[4][H];
    __shared__ __align__(16) float w2[H];
    __shared__ __align__(16) float sc[4][NK];

    // per-wave query row into LDS (coalesced)
    qv[w][l] = qp[((size_t)b * NQ + q0 + w) * H + l];

    // wv: each lane holds wv[l]; butterfly-sum for sum_wv; w2 = -2*wv
    const float wvl = wv[l];
    float swv = wvl;
#pragma unroll
    for (int off = 32; off > 0; off >>= 1) swv += __shfl_xor(swv, off);
    if (w == 0) w2[l] = -2.f * wvl;

    const int vlen = valid_lens[b];

    // ---- score phase: 4 key tiles of 128 ----
    for (int kt = 0; kt < NK / KT; ++kt) {
        if (kt * KT < vlen) {
            __syncthreads();   // protect previous tile's reads + first-iter qv/w2
            // stage 128 keys x 64 h = 2048 float4, 8 per thread, coalesced
            const float* src = kp + ((size_t)b * NK + kt * KT) * H;
#pragma unroll
            for (int j = 0; j < 8; ++j) {
                int idx4 = t + j * 256;
                int kk = idx4 >> 4;            // 16 float4 per 64-float row
                int hb = (idx4 & 15) * 4;
                float4 v = ((const float4*)src)[idx4];
                *(float4*)&kT[kk * KPAD + hb] = v;
            }
            __syncthreads();

            // wave w / query w; lane handles tile-keys l and l+64
            const float* qrow = &qv[w][0];
            const float* k0r = &kT[l * KPAD];
            const float* k1r = &kT[(l + 64) * KPAD];
            float s0 = 0.f, s1 = 0.f;
#pragma unroll
            for (int h4 = 0; h4 < H / 4; ++h4) {
                float4 qq = *(const float4*)&qrow[h4 * 4];
                float4 ww = *(const float4*)&w2[h4 * 4];
                float4 k0 = *(const float4*)&k0r[h4 * 4];
                float4 k1 = *(const float4*)&k1r[h4 * 4];
                const float C = 2.f * LOG2E;
                float r;
                r = __builtin_amdgcn_rcpf(__builtin_amdgcn_exp2f((qq.x + k0.x) * C) + 1.f);
                s0 = fmaf(ww.x, r, s0);
                r = __builtin_amdgcn_rcpf(__builtin_amdgcn_exp2f((qq.y + k0.y) * C) + 1.f);
                s0 = fmaf(ww.y, r, s0);
                r = __builtin_amdgcn_rcpf(__builtin_amdgcn_exp2f((qq.z + k0.z) * C) + 1.f);
                s0 = fmaf(ww.z, r, s0);
                r = __builtin_amdgcn_rcpf(__builtin_amdgcn_exp2f((qq.w + k0.w) * C) + 1.f);
                s0 = fmaf(ww.w, r, s0);
                r = __builtin_amdgcn_rcpf(__builtin_amdgcn_exp2f((qq.x + k1.x) * C) + 1.f);
                s1 = fmaf(ww.x, r, s1);
                r = __builtin_amdgcn_rcpf(__builtin_amdgcn_exp2f((qq.y + k1.y) * C) + 1.f);
                s1 = fmaf(ww.y, r, s1);
                r = __builtin_amdgcn_rcpf(__builtin_amdgcn_exp2f((qq.z + k1.z) * C) + 1.f);
                s1 = fmaf(ww.z, r, s1);
                r = __builtin_amdgcn_rcpf(__builtin_amdgcn_exp2f((qq.w + k1.w) * C) + 1.f);
                s1 = fmaf(ww.w, r, s1);
            }
            int kg0 = kt * KT + l;
            int kg1 = kt * KT + l + 64;
            sc[w][kg0] = (kg0 < vlen) ? (s0 + swv) : NEG;
            sc[w][kg1] = (kg1 < vlen) ? (s1 + swv) : NEG;
        } else {
            // fully masked tile: just write NEG (wave-private row)
            sc[w][kt * KT + l]      = NEG;
            sc[w][kt * KT + l + 64] = NEG;
        }
    }

    // ---- softmax over sc[w][0..511] (wave-private row, no barrier needed) ----
    float vals[8];
    float m = -INFINITY;
#pragma unroll
    for (int j = 0; j < 8; ++j) {
        vals[j] = sc[w][l + j * 64];
        m = fmaxf(m, vals[j]);
    }
#pragma unroll
    for (int off = 32; off > 0; off >>= 1) m = fmaxf(m, __shfl_xor(m, off));
    float sum = 0.f;
#pragma unroll
    for (int j = 0; j < 8; ++j) {
        float p = __builtin_amdgcn_exp2f((vals[j] - m) * LOG2E);
        vals[j] = p;
        sum += p;
    }
#pragma unroll
    for (int off = 32; off > 0; off >>= 1) sum += __shfl_xor(sum, off);
    const float rinv = __builtin_amdgcn_rcpf(sum);
#pragma unroll
    for (int j = 0; j < 8; ++j) sc[w][l + j * 64] = vals[j] * rinv;

    // ---- output: out[b, q0+w, v], lane l owns v = 4l..4l+3 ----
    // attn[k] == 0 exactly for k >= vlen, so loop only to vlen.
    float4 acc = {0.f, 0.f, 0.f, 0.f};
    const float* Vb = values + (size_t)b * NK * DV;
    for (int k = 0; k < vlen; ++k) {
        float a = sc[w][k];
        float4 vv = *(const float4*)&Vb[(size_t)k * DV + 4 * l];
        acc.x = fmaf(a, vv.x, acc.x);
        acc.y = fmaf(a, vv.y, acc.y);
        acc.z = fmaf(a, vv.z, acc.z);
        acc.w = fmaf(a, vv.w, acc.w);
    }
    *(float4*)&out[((size_t)b * NQ + q0 + w) * DV + 4 * l] = acc;
}

// ---------------------------------------------------------------------------
extern "C" void kernel_launch(void* const* d_in, const int* in_sizes, int n_in,
                              void* d_out, int out_size, void* d_ws, size_t ws_size,
                              hipStream_t stream) {
    const float* queries    = (const float*)d_in[0];
    const float* keys       = (const float*)d_in[1];
    const float* values     = (const float*)d_in[2];
    const int*   valid_lens = (const int*)d_in[3];
    const float* Wq         = (const float*)d_in[4];
    const float* Wk         = (const float*)d_in[5];
    const float* wv         = (const float*)d_in[6];
    float* out = (float*)d_out;

    float* qp = (float*)d_ws;                   // [B, NQ, H]
    float* kp = qp + (size_t)B * NQ * H;        // [B, NK, H]

    // projections: (2048 + 4096) rows / 4 per block
    proj_kernel<<<(B * NQ + B * NK) / 4, 256, 0, stream>>>(
        queries, keys, Wq, Wk, qp, kp);

    // attention: one block per (batch, 4-query tile)
    attn_kernel<<<B * (NQ / 4), 256, 0, stream>>>(
        qp, kp, values, valid_lens, wv, out);
}

// Round 2
// 105.507 us; speedup vs baseline: 1.1500x; 1.1500x over previous
//
#include <hip/hip_runtime.h>
#include <hip/hip_bf16.h>

// Problem constants (match reference)
constexpr int B  = 8;
constexpr int NQ = 256;
constexpr int NK = 512;
constexpr int D  = 256;   // DQ == DK == 256
constexpr int DV = 256;
constexpr int H  = 64;
constexpr float NEG = -1e6f;
constexpr float LOG2E = 1.4426950408889634f;

// ---------------------------------------------------------------------------
// Kernel 1: project queries and keys.  out[r,h] = sum_d in[r,d] * W[d,h]
// 8 rows per block, 256 threads; thread (h = t&63, g = t>>6) computes rows
// g and g+4  ->  2 FMAs per W load (halves VMEM instr count vs 1 row/thread).
// ---------------------------------------------------------------------------
constexpr int RPB = 8;   // rows per block

__global__ __launch_bounds__(256) void proj_kernel(
    const float* __restrict__ queries, const float* __restrict__ keys,
    const float* __restrict__ Wq, const float* __restrict__ Wk,
    float* __restrict__ qp, float* __restrict__ kp)
{
    const int r0 = blockIdx.x * RPB;
    const bool isQ = (r0 < B * NQ);         // q-rows first (2048), then k-rows (4096)
    const float* src = isQ ? queries + (size_t)r0 * D
                           : keys + (size_t)(r0 - B * NQ) * D;
    const float* W   = isQ ? Wq : Wk;
    float* out       = isQ ? qp + (size_t)r0 * H
                           : kp + (size_t)(r0 - B * NQ) * H;

    __shared__ __align__(16) float rows[RPB][D];   // 8 KB
    // 8 rows * 256 floats = 512 float4; 256 threads -> 2 each (coalesced)
#pragma unroll
    for (int j = 0; j < 2; ++j)
        ((float4*)&rows[0][0])[threadIdx.x + j * 256] =
            ((const float4*)src)[threadIdx.x + j * 256];
    __syncthreads();

    const int h = threadIdx.x & 63;
    const int g = threadIdx.x >> 6;         // rows g and g+4
    float s0 = 0.f, s1 = 0.f;
#pragma unroll 2
    for (int d4 = 0; d4 < D / 4; ++d4) {
        float w0 = W[(d4 * 4 + 0) * H + h];
        float w1 = W[(d4 * 4 + 1) * H + h];
        float w2 = W[(d4 * 4 + 2) * H + h];
        float w3 = W[(d4 * 4 + 3) * H + h];
        float4 ra = *(const float4*)&rows[g][d4 * 4];
        float4 rb = *(const float4*)&rows[g + 4][d4 * 4];
        s0 = fmaf(ra.x, w0, s0);  s1 = fmaf(rb.x, w0, s1);
        s0 = fmaf(ra.y, w1, s0);  s1 = fmaf(rb.y, w1, s1);
        s0 = fmaf(ra.z, w2, s0);  s1 = fmaf(rb.z, w2, s1);
        s0 = fmaf(ra.w, w3, s0);  s1 = fmaf(rb.w, w3, s1);
    }
    out[g * H + h]       = s0;
    out[(g + 4) * H + h] = s1;
}

// ---------------------------------------------------------------------------
// Kernel 2: scores + masked softmax + attn@V.
// Grid: B * (NQ/4) = 512 blocks, 512 threads = 8 waves (2 waves per query).
//   wave w: query (w>>1), key-half (w&1).
// Keys staged in LDS tiles of 128, layout [k][h] stride 68 (b128 reads are
// 2-way-in-phase -> conflict-free).  AV phase is block-cooperative: wave w
// covers keys [64w,64w+64), accumulating partials for ALL 4 queries from each
// V row load (4x less V traffic); partials reduced via LDS aliased over kT.
// tanh(x) = 1 - 2*rcp(exp2(2x*log2e)+1); score = sum_wv + sum_h (-2 wv_h) r_h.
// ---------------------------------------------------------------------------
constexpr int KT   = 128;   // keys per LDS tile
constexpr int KPAD = 68;    // row stride (floats): 272 B, 16B-aligned

#define FMA4(acc, a, v) \
    acc.x = fmaf(a, v.x, acc.x); acc.y = fmaf(a, v.y, acc.y); \
    acc.z = fmaf(a, v.z, acc.z); acc.w = fmaf(a, v.w, acc.w);

__global__ __launch_bounds__(512, 4) void attn_kernel(
    const float* __restrict__ qp, const float* __restrict__ kp,
    const float* __restrict__ values, const int* __restrict__ valid_lens,
    const float* __restrict__ wv, float* __restrict__ out)
{
    const int b    = blockIdx.x >> 6;        // batch
    const int q0   = (blockIdx.x & 63) * 4;  // first query of this block
    const int t    = threadIdx.x;
    const int w    = t >> 6;                 // wave id (0..7)
    const int l    = t & 63;                 // lane
    const int qloc = w >> 1;                 // local query (0..3)
    const int half = w & 1;                  // key-half within tile

    __shared__ __align__(16) float kT[KT * KPAD];  // 34816 B; aliased as pt[8][4][256] in AV
    __shared__ __align__(16) float qv[4][H];
    __shared__ __align__(16) float w2[H];
    __shared__ __align__(16) float sc[4][NK];

    // per-query row into LDS (one of the wave pair)
    if (half == 0)
        qv[qloc][l] = qp[((size_t)b * NQ + q0 + qloc) * H + l];

    // wv: lane l holds wv[l]; butterfly-sum for sum_wv; w2 = -2*wv
    const float wvl = wv[l];
    float swv = wvl;
#pragma unroll
    for (int off = 32; off > 0; off >>= 1) swv += __shfl_xor(swv, off);
    if (w == 0) w2[l] = -2.f * wvl;

    const int vlen = valid_lens[b];

    // ---- score phase: 4 key tiles of 128; wave handles 64 keys/tile ----
    for (int kt = 0; kt < NK / KT; ++kt) {
        const int kg = kt * KT + half * 64 + l;   // this lane's global key
        if (kt * KT < vlen) {
            __syncthreads();   // protect previous tile's reads + first-iter qv/w2
            // stage 128 keys x 64 h = 2048 float4, 4 per thread, coalesced
            const float* src = kp + ((size_t)b * NK + kt * KT) * H;
#pragma unroll
            for (int j = 0; j < 4; ++j) {
                int idx4 = t + j * 512;
                int kk = idx4 >> 4;            // 16 float4 per 64-float row
                int hb = (idx4 & 15) * 4;
                float4 v = ((const float4*)src)[idx4];
                *(float4*)&kT[kk * KPAD + hb] = v;
            }
            __syncthreads();

            const float* qrow = &qv[qloc][0];
            const float* krow = &kT[(half * 64 + l) * KPAD];
            float s0 = 0.f;
#pragma unroll
            for (int h4 = 0; h4 < H / 4; ++h4) {
                float4 qq = *(const float4*)&qrow[h4 * 4];
                float4 ww = *(const float4*)&w2[h4 * 4];
                float4 kk = *(const float4*)&krow[h4 * 4];
                const float C = 2.f * LOG2E;
                float r;
                r = __builtin_amdgcn_rcpf(__builtin_amdgcn_exp2f((qq.x + kk.x) * C) + 1.f);
                s0 = fmaf(ww.x, r, s0);
                r = __builtin_amdgcn_rcpf(__builtin_amdgcn_exp2f((qq.y + kk.y) * C) + 1.f);
                s0 = fmaf(ww.y, r, s0);
                r = __builtin_amdgcn_rcpf(__builtin_amdgcn_exp2f((qq.z + kk.z) * C) + 1.f);
                s0 = fmaf(ww.z, r, s0);
                r = __builtin_amdgcn_rcpf(__builtin_amdgcn_exp2f((qq.w + kk.w) * C) + 1.f);
                s0 = fmaf(ww.w, r, s0);
            }
            sc[qloc][kg] = (kg < vlen) ? (s0 + swv) : NEG;
        } else {
            sc[qloc][kg] = NEG;   // fully masked tile
        }
    }
    __syncthreads();   // sc rows now complete (each written by 2 waves)

    // ---- softmax over sc[qloc][0..511] (both waves of pair compute identically) ----
    float vals[8];
    float m = -INFINITY;
#pragma unroll
    for (int j = 0; j < 8; ++j) {
        vals[j] = sc[qloc][l + j * 64];
        m = fmaxf(m, vals[j]);
    }
#pragma unroll
    for (int off = 32; off > 0; off >>= 1) m = fmaxf(m, __shfl_xor(m, off));
    float sum = 0.f;
#pragma unroll
    for (int j = 0; j < 8; ++j) {
        float p = __builtin_amdgcn_exp2f((vals[j] - m) * LOG2E);
        vals[j] = p;
        sum += p;
    }
#pragma unroll
    for (int off = 32; off > 0; off >>= 1) sum += __shfl_xor(sum, off);
    const float rinv = __builtin_amdgcn_rcpf(sum);
    // each wave of the pair writes its 4 of the 8 chunks (compile-time idx)
    if (half == 0) {
        sc[qloc][l + 0 * 64] = vals[0] * rinv;
        sc[qloc][l + 1 * 64] = vals[1] * rinv;
        sc[qloc][l + 2 * 64] = vals[2] * rinv;
        sc[qloc][l + 3 * 64] = vals[3] * rinv;
    } else {
        sc[qloc][l + 4 * 64] = vals[4] * rinv;
        sc[qloc][l + 5 * 64] = vals[5] * rinv;
        sc[qloc][l + 6 * 64] = vals[6] * rinv;
        sc[qloc][l + 7 * 64] = vals[7] * rinv;
    }
    __syncthreads();   // all normalized weights visible to all waves

    // ---- AV: wave w covers keys [64w, 64w+64); partials for all 4 queries ----
    // attn[k] == 0 exactly for k >= vlen (exp2 underflow), so rounding the
    // count up to a multiple of 4 is exact.
    float4 acc0 = {0,0,0,0}, acc1 = {0,0,0,0}, acc2 = {0,0,0,0}, acc3 = {0,0,0,0};
    const float* Vb = values + (size_t)b * NK * DV;
    const int kbeg = w * 64;
    const int kend = min(vlen - kbeg, 64);
    const int kcnt = (kend > 0) ? ((kend + 3) >> 2) : 0;   // 4-key chunks
    for (int c = 0; c < kcnt; ++c) {
        const int k = kbeg + 4 * c;
        float4 a0 = *(const float4*)&sc[0][k];
        float4 a1 = *(const float4*)&sc[1][k];
        float4 a2 = *(const float4*)&sc[2][k];
        float4 a3 = *(const float4*)&sc[3][k];
        const float* vr = Vb + (size_t)k * DV + 4 * l;
        float4 v0 = *(const float4*)(vr);
        float4 v1 = *(const float4*)(vr + DV);
        float4 v2 = *(const float4*)(vr + 2 * DV);
        float4 v3 = *(const float4*)(vr + 3 * DV);
        FMA4(acc0, a0.x, v0); FMA4(acc0, a0.y, v1); FMA4(acc0, a0.z, v2); FMA4(acc0, a0.w, v3);
        FMA4(acc1, a1.x, v0); FMA4(acc1, a1.y, v1); FMA4(acc1, a1.z, v2); FMA4(acc1, a1.w, v3);
        FMA4(acc2, a2.x, v0); FMA4(acc2, a2.y, v1); FMA4(acc2, a2.z, v2); FMA4(acc2, a2.w, v3);
        FMA4(acc3, a3.x, v0); FMA4(acc3, a3.y, v1); FMA4(acc3, a3.z, v2); FMA4(acc3, a3.w, v3);
    }

    // partials into LDS (alias over kT: 8 waves * 4 q * 256 v = 32 KB <= 34.8 KB)
    float* pt = kT;
    *(float4*)&pt[(w * 4 + 0) * 256 + 4 * l] = acc0;
    *(float4*)&pt[(w * 4 + 1) * 256 + 4 * l] = acc1;
    *(float4*)&pt[(w * 4 + 2) * 256 + 4 * l] = acc2;
    *(float4*)&pt[(w * 4 + 3) * 256 + 4 * l] = acc3;
    __syncthreads();

    // waves 0..3: final reduce + store for query w
    if (w < 4) {
        float4 r = {0,0,0,0};
#pragma unroll
        for (int s = 0; s < 8; ++s) {
            float4 p = *(const float4*)&pt[(s * 4 + w) * 256 + 4 * l];
            r.x += p.x; r.y += p.y; r.z += p.z; r.w += p.w;
        }
        *(float4*)&out[((size_t)b * NQ + q0 + w) * DV + 4 * l] = r;
    }
}

// ---------------------------------------------------------------------------
extern "C" void kernel_launch(void* const* d_in, const int* in_sizes, int n_in,
                              void* d_out, int out_size, void* d_ws, size_t ws_size,
                              hipStream_t stream) {
    const float* queries    = (const float*)d_in[0];
    const float* keys       = (const float*)d_in[1];
    const float* values     = (const float*)d_in[2];
    const int*   valid_lens = (const int*)d_in[3];
    const float* Wq         = (const float*)d_in[4];
    const float* Wk         = (const float*)d_in[5];
    const float* wv         = (const float*)d_in[6];
    float* out = (float*)d_out;

    float* qp = (float*)d_ws;                   // [B, NQ, H]
    float* kp = qp + (size_t)B * NQ * H;        // [B, NK, H]

    // projections: (2048 + 4096) rows / 8 per block
    proj_kernel<<<(B * NQ + B * NK) / RPB, 256, 0, stream>>>(
        queries, keys, Wq, Wk, qp, kp);

    // attention: one block per (batch, 4-query tile); 8 waves
    attn_kernel<<<B * (NQ / 4), 512, 0, stream>>>(
        qp, kp, values, valid_lens, wv, out);
}

// Round 3
// 102.740 us; speedup vs baseline: 1.1809x; 1.0269x over previous
//
#include <hip/hip_runtime.h>
#include <hip/hip_bf16.h>

// Problem constants (match reference)
constexpr int B  = 8;
constexpr int NQ = 256;
constexpr int NK = 512;
constexpr int D  = 256;   // DQ == DK == 256
constexpr int DV = 256;
constexpr int H  = 64;
constexpr float NEG = -1e6f;
constexpr float LOG2E = 1.4426950408889634f;
constexpr float CSCALE = 2.f * LOG2E;   // folded into projected q,k

// ---------------------------------------------------------------------------
// Kernel 1: project queries and keys, PRE-SCALED by 2*log2e.
//   out[r,h] = CSCALE * sum_d in[r,d] * W[d,h]
// 16 rows per block, 256 threads; thread (h = t&63, g = t>>6) computes rows
// g, g+4, g+8, g+12  ->  4 FMAs per W load.  Row reads are wave-uniform LDS
// broadcasts (g is wave-uniform), conflict-free.
// ---------------------------------------------------------------------------
constexpr int RPB = 16;   // rows per block

__global__ __launch_bounds__(256) void proj_kernel(
    const float* __restrict__ queries, const float* __restrict__ keys,
    const float* __restrict__ Wq, const float* __restrict__ Wk,
    float* __restrict__ qp, float* __restrict__ kp)
{
    const int r0 = blockIdx.x * RPB;
    const bool isQ = (r0 < B * NQ);         // q-rows first (2048), then k-rows (4096)
    const float* src = isQ ? queries + (size_t)r0 * D
                           : keys + (size_t)(r0 - B * NQ) * D;
    const float* W   = isQ ? Wq : Wk;
    float* out       = isQ ? qp + (size_t)r0 * H
                           : kp + (size_t)(r0 - B * NQ) * H;

    __shared__ __align__(16) float rows[RPB][D];   // 16 KB
    // 16 rows * 64 float4 = 1024 float4; 256 threads -> 4 each (coalesced)
#pragma unroll
    for (int j = 0; j < 4; ++j)
        ((float4*)&rows[0][0])[threadIdx.x + j * 256] =
            ((const float4*)src)[threadIdx.x + j * 256];
    __syncthreads();

    const int h = threadIdx.x & 63;
    const int g = threadIdx.x >> 6;         // wave id; rows g, g+4, g+8, g+12
    float s0 = 0.f, s1 = 0.f, s2 = 0.f, s3 = 0.f;
#pragma unroll 2
    for (int d4 = 0; d4 < D / 4; ++d4) {
        float w0 = W[(d4 * 4 + 0) * H + h];
        float w1 = W[(d4 * 4 + 1) * H + h];
        float w2 = W[(d4 * 4 + 2) * H + h];
        float w3 = W[(d4 * 4 + 3) * H + h];
        float4 ra = *(const float4*)&rows[g][d4 * 4];
        float4 rb = *(const float4*)&rows[g + 4][d4 * 4];
        float4 rc = *(const float4*)&rows[g + 8][d4 * 4];
        float4 rd = *(const float4*)&rows[g + 12][d4 * 4];
        s0 = fmaf(ra.x, w0, s0);  s1 = fmaf(rb.x, w0, s1);
        s2 = fmaf(rc.x, w0, s2);  s3 = fmaf(rd.x, w0, s3);
        s0 = fmaf(ra.y, w1, s0);  s1 = fmaf(rb.y, w1, s1);
        s2 = fmaf(rc.y, w1, s2);  s3 = fmaf(rd.y, w1, s3);
        s0 = fmaf(ra.z, w2, s0);  s1 = fmaf(rb.z, w2, s1);
        s2 = fmaf(rc.z, w2, s2);  s3 = fmaf(rd.z, w2, s3);
        s0 = fmaf(ra.w, w3, s0);  s1 = fmaf(rb.w, w3, s1);
        s2 = fmaf(rc.w, w3, s2);  s3 = fmaf(rd.w, w3, s3);
    }
    out[g * H + h]        = s0 * CSCALE;
    out[(g + 4) * H + h]  = s1 * CSCALE;
    out[(g + 8) * H + h]  = s2 * CSCALE;
    out[(g + 12) * H + h] = s3 * CSCALE;
}

// ---------------------------------------------------------------------------
// Kernel 2: scores + masked softmax + attn@V.
// Grid: 512 blocks, 512 threads = 8 waves.  b = blockIdx&7 so the 64 blocks
// of one batch land on one XCD (round-robin dispatch) -> V[b],K[b] stay in
// that XCD's 4 MiB L2.  Wave w: query (w>>1), key-half (w&1) for scores.
// Keys staged in LDS tiles of 128, stride 68 (b128 quarter-wave phase -> 2-way
// = conflict-free).  q,k pre-scaled so tanh elem = rcp(exp2(q+k)+1), no mul.
// AV: 4-key chunks round-robined across all 8 waves (load-balanced in vlen),
// each chunk's V rows FMA'd into partials for ALL 4 queries; LDS reduce.
// ---------------------------------------------------------------------------
constexpr int KT   = 128;   // keys per LDS tile
constexpr int KPAD = 68;    // row stride (floats): 272 B, 16B-aligned

#define FMA4(acc, a, v) \
    acc.x = fmaf(a, v.x, acc.x); acc.y = fmaf(a, v.y, acc.y); \
    acc.z = fmaf(a, v.z, acc.z); acc.w = fmaf(a, v.w, acc.w);

__global__ __launch_bounds__(512, 4) void attn_kernel(
    const float* __restrict__ qp, const float* __restrict__ kp,
    const float* __restrict__ values, const int* __restrict__ valid_lens,
    const float* __restrict__ wv, float* __restrict__ out)
{
    const int b    = blockIdx.x & 7;         // batch <-> XCD
    const int q0   = (blockIdx.x >> 3) * 4;  // first query of this block
    const int t    = threadIdx.x;
    const int w    = t >> 6;                 // wave id (0..7)
    const int l    = t & 63;                 // lane
    const int qloc = w >> 1;                 // local query (0..3)
    const int half = w & 1;                  // key-half within tile

    __shared__ __align__(16) float kT[KT * KPAD];  // 34816 B; aliased as pt[8][4][256] in AV
    __shared__ __align__(16) float qv[4][H];
    __shared__ __align__(16) float w2[H];
    __shared__ __align__(16) float sc[4][NK];

    // per-query row into LDS (one of the wave pair)
    if (half == 0)
        qv[qloc][l] = qp[((size_t)b * NQ + q0 + qloc) * H + l];

    // wv: lane l holds wv[l]; butterfly-sum for sum_wv; w2 = -2*wv
    const float wvl = wv[l];
    float swv = wvl;
#pragma unroll
    for (int off = 32; off > 0; off >>= 1) swv += __shfl_xor(swv, off);
    if (w == 0) w2[l] = -2.f * wvl;

    const int vlen = valid_lens[b];

    // ---- score phase: 4 key tiles of 128; wave handles 64 keys/tile ----
    for (int kt = 0; kt < NK / KT; ++kt) {
        const int kg = kt * KT + half * 64 + l;   // this lane's global key
        if (kt * KT < vlen) {
            __syncthreads();   // protect previous tile's reads + first-iter qv/w2
            // stage 128 keys x 64 h = 2048 float4, 4 per thread, coalesced
            const float* src = kp + ((size_t)b * NK + kt * KT) * H;
#pragma unroll
            for (int j = 0; j < 4; ++j) {
                int idx4 = t + j * 512;
                int kk = idx4 >> 4;            // 16 float4 per 64-float row
                int hb = (idx4 & 15) * 4;
                float4 v = ((const float4*)src)[idx4];
                *(float4*)&kT[kk * KPAD + hb] = v;
            }
            __syncthreads();

            const float* qrow = &qv[qloc][0];
            const float* krow = &kT[(half * 64 + l) * KPAD];
            float s0 = 0.f;
#pragma unroll
            for (int h4 = 0; h4 < H / 4; ++h4) {
                float4 qq = *(const float4*)&qrow[h4 * 4];
                float4 ww = *(const float4*)&w2[h4 * 4];
                float4 kk = *(const float4*)&krow[h4 * 4];
                float r;
                r = __builtin_amdgcn_rcpf(__builtin_amdgcn_exp2f(qq.x + kk.x) + 1.f);
                s0 = fmaf(ww.x, r, s0);
                r = __builtin_amdgcn_rcpf(__builtin_amdgcn_exp2f(qq.y + kk.y) + 1.f);
                s0 = fmaf(ww.y, r, s0);
                r = __builtin_amdgcn_rcpf(__builtin_amdgcn_exp2f(qq.z + kk.z) + 1.f);
                s0 = fmaf(ww.z, r, s0);
                r = __builtin_amdgcn_rcpf(__builtin_amdgcn_exp2f(qq.w + kk.w) + 1.f);
                s0 = fmaf(ww.w, r, s0);
            }
            sc[qloc][kg] = (kg < vlen) ? (s0 + swv) : NEG;
        } else {
            sc[qloc][kg] = NEG;   // fully masked tile
        }
    }
    __syncthreads();   // sc rows now complete (each written by 2 waves)

    // ---- softmax over sc[qloc][0..511] (both waves of pair compute identically) ----
    float vals[8];
    float m = -INFINITY;
#pragma unroll
    for (int j = 0; j < 8; ++j) {
        vals[j] = sc[qloc][l + j * 64];
        m = fmaxf(m, vals[j]);
    }
#pragma unroll
    for (int off = 32; off > 0; off >>= 1) m = fmaxf(m, __shfl_xor(m, off));
    float sum = 0.f;
#pragma unroll
    for (int j = 0; j < 8; ++j) {
        float p = __builtin_amdgcn_exp2f((vals[j] - m) * LOG2E);
        vals[j] = p;
        sum += p;
    }
#pragma unroll
    for (int off = 32; off > 0; off >>= 1) sum += __shfl_xor(sum, off);
    const float rinv = __builtin_amdgcn_rcpf(sum);
    // each wave of the pair writes its 4 of the 8 chunks (compile-time idx)
    if (half == 0) {
        sc[qloc][l + 0 * 64] = vals[0] * rinv;
        sc[qloc][l + 1 * 64] = vals[1] * rinv;
        sc[qloc][l + 2 * 64] = vals[2] * rinv;
        sc[qloc][l + 3 * 64] = vals[3] * rinv;
    } else {
        sc[qloc][l + 4 * 64] = vals[4] * rinv;
        sc[qloc][l + 5 * 64] = vals[5] * rinv;
        sc[qloc][l + 6 * 64] = vals[6] * rinv;
        sc[qloc][l + 7 * 64] = vals[7] * rinv;
    }
    __syncthreads();   // all normalized weights visible to all waves

    // ---- AV: 4-key chunks round-robined across the 8 waves (balanced) ----
    // attn[k] == 0 exactly for k >= vlen (exp2 underflow), so rounding the
    // chunk count up to a multiple of 4 keys is exact.
    float4 acc0 = {0,0,0,0}, acc1 = {0,0,0,0}, acc2 = {0,0,0,0}, acc3 = {0,0,0,0};
    const float* Vb = values + (size_t)b * NK * DV;
    const int nchunks = (vlen + 3) >> 2;
    for (int c = w; c < nchunks; c += 8) {
        const int k = 4 * c;
        float4 a0 = *(const float4*)&sc[0][k];
        float4 a1 = *(const float4*)&sc[1][k];
        float4 a2 = *(const float4*)&sc[2][k];
        float4 a3 = *(const float4*)&sc[3][k];
        const float* vr = Vb + (size_t)k * DV + 4 * l;
        float4 v0 = *(const float4*)(vr);
        float4 v1 = *(const float4*)(vr + DV);
        float4 v2 = *(const float4*)(vr + 2 * DV);
        float4 v3 = *(const float4*)(vr + 3 * DV);
        FMA4(acc0, a0.x, v0); FMA4(acc0, a0.y, v1); FMA4(acc0, a0.z, v2); FMA4(acc0, a0.w, v3);
        FMA4(acc1, a1.x, v0); FMA4(acc1, a1.y, v1); FMA4(acc1, a1.z, v2); FMA4(acc1, a1.w, v3);
        FMA4(acc2, a2.x, v0); FMA4(acc2, a2.y, v1); FMA4(acc2, a2.z, v2); FMA4(acc2, a2.w, v3);
        FMA4(acc3, a3.x, v0); FMA4(acc3, a3.y, v1); FMA4(acc3, a3.z, v2); FMA4(acc3, a3.w, v3);
    }

    // partials into LDS (alias over kT: 8 waves * 4 q * 256 v = 32 KB <= 34.8 KB)
    float* pt = kT;
    *(float4*)&pt[(w * 4 + 0) * 256 + 4 * l] = acc0;
    *(float4*)&pt[(w * 4 + 1) * 256 + 4 * l] = acc1;
    *(float4*)&pt[(w * 4 + 2) * 256 + 4 * l] = acc2;
    *(float4*)&pt[(w * 4 + 3) * 256 + 4 * l] = acc3;
    __syncthreads();

    // waves 0..3: final reduce + store for query w
    if (w < 4) {
        float4 r = {0,0,0,0};
#pragma unroll
        for (int s = 0; s < 8; ++s) {
            float4 p = *(const float4*)&pt[(s * 4 + w) * 256 + 4 * l];
            r.x += p.x; r.y += p.y; r.z += p.z; r.w += p.w;
        }
        *(float4*)&out[((size_t)b * NQ + q0 + w) * DV + 4 * l] = r;
    }
}

// ---------------------------------------------------------------------------
extern "C" void kernel_launch(void* const* d_in, const int* in_sizes, int n_in,
                              void* d_out, int out_size, void* d_ws, size_t ws_size,
                              hipStream_t stream) {
    const float* queries    = (const float*)d_in[0];
    const float* keys       = (const float*)d_in[1];
    const float* values     = (const float*)d_in[2];
    const int*   valid_lens = (const int*)d_in[3];
    const float* Wq         = (const float*)d_in[4];
    const float* Wk         = (const float*)d_in[5];
    const float* wv         = (const float*)d_in[6];
    float* out = (float*)d_out;

    float* qp = (float*)d_ws;                   // [B, NQ, H]  (pre-scaled by 2*log2e)
    float* kp = qp + (size_t)B * NQ * H;        // [B, NK, H]  (pre-scaled by 2*log2e)

    // projections: (2048 + 4096) rows / 16 per block
    proj_kernel<<<(B * NQ + B * NK) / RPB, 256, 0, stream>>>(
        queries, keys, Wq, Wk, qp, kp);

    // attention: one block per (batch, 4-query tile); batch = blockIdx&7 (XCD-local)
    attn_kernel<<<B * (NQ / 4), 512, 0, stream>>>(
        qp, kp, values, valid_lens, wv, out);
}